// Round 12
// baseline (277.199 us; speedup 1.0000x reference)
//
#include <hip/hip_runtime.h>

// ---------------------------------------------------------------------------
// Round 17: GEMMs ported to the 8-phase/counted-vmcnt template (T3+T4),
// BN=128 parameter lane: BM=256 BN=128 BK=64, 512 thr (8 waves 2Mx4N),
// grid 24x32=768 (=3 exact CU rounds; MODE1: 8x32=256 = 1/CU). LDS 96KB
// double-buffered; 2 phases/K-tile of 16 MFMA; staging of tile t+2 into
// freed regions only (region ledger proven); vmcnt(6) once per tile --
// no drain in the loop. Epilogue scatter verbatim from gemm128.
// flash9b (77.6us, split fence) and prep unchanged.
// B=4, S=2048, NH=16, DH=64, E=1024. fp32 I/O, bf16 compute, fp32 accum.
// ---------------------------------------------------------------------------

typedef __attribute__((ext_vector_type(8))) short short8;
typedef __attribute__((ext_vector_type(4))) float floatx4;

#define SCL 0.1803368801111244f   // (1/8) * log2(e), folded into Q projection

__device__ __forceinline__ unsigned short f2bf(float f) {
  unsigned int x = __float_as_uint(f);
  x += 0x7fffu + ((x >> 16) & 1u);   // RNE
  return (unsigned short)(x >> 16);
}

__device__ __forceinline__ void gload_lds16(const unsigned short* g, unsigned short* lds) {
  __builtin_amdgcn_global_load_lds(
      (const __attribute__((address_space(1))) void*)g,
      (__attribute__((address_space(3))) void*)lds, 16, 0, 0);
}

// ---------------- fused prep: cvt_x + W_QKV transpose + W_O transpose ------
__global__ __launch_bounds__(256) void prep_kernel(
    const float* __restrict__ X,  unsigned short* __restrict__ Xb,
    const float* __restrict__ Wq, const float* __restrict__ Wk,
    const float* __restrict__ Wv, unsigned short* __restrict__ Bt,
    const float* __restrict__ Wo, unsigned short* __restrict__ Wt)
{
  __shared__ unsigned short T[64 * 72];
  const int bid = blockIdx.x, t = threadIdx.x;
  if (bid < 8192) {                                  // ---- x fp32 -> bf16
    int idx = ((bid << 8) + t) << 2;
    float4 f = *(const float4*)(X + idx);
    unsigned short u[4] = { f2bf(f.x), f2bf(f.y), f2bf(f.z), f2bf(f.w) };
    *(uint2*)(Xb + idx) = *(uint2*)u;
  } else if (bid < 8960) {                           // ---- W_{Q,K,V} transpose
    int b2 = bid - 8192;
    int e0 = (b2 & 15) << 6, nn = (b2 >> 4) & 15, proj = b2 >> 8;
    const float* W = (proj == 0) ? Wq : (proj == 1) ? Wk : Wv;
    const float* src = W + ((size_t)nn << 16) + ((size_t)e0 << 6);
#pragma unroll
    for (int rnd = 0; rnd < 4; ++rnd) {
      int off = (rnd << 10) + (t << 2);
      float4 f = *(const float4*)(src + off);
      int r = off >> 6, h = off & 63;
      T[r * 72 + h]     = f2bf(f.x);
      T[r * 72 + h + 1] = f2bf(f.y);
      T[r * 72 + h + 2] = f2bf(f.z);
      T[r * 72 + h + 3] = f2bf(f.w);
    }
    __syncthreads();
    const int h = t >> 2, ck = t & 3;
    size_t orow = ((size_t)((proj << 10) + (nn << 6) + h) << 10) + e0 + (ck << 4);
#pragma unroll
    for (int g = 0; g < 2; ++g) {
      unsigned short v[8];
#pragma unroll
      for (int j = 0; j < 8; ++j) v[j] = T[((ck << 4) + (g << 3) + j) * 72 + h];
      *(int4*)(Bt + orow + (g << 3)) = *(int4*)v;
    }
  } else {                                           // ---- W_O transpose
    int b2 = bid - 8960;
    int e0 = (b2 & 15) << 6, k0 = (b2 >> 4) << 6;
#pragma unroll
    for (int rnd = 0; rnd < 4; ++rnd) {
      int r = (rnd << 4) + (t >> 4);
      int c = (t & 15) << 2;
      float4 f = *(const float4*)(Wo + ((size_t)(k0 + r) << 10) + e0 + c);
      T[r * 72 + c]     = f2bf(f.x);
      T[r * 72 + c + 1] = f2bf(f.y);
      T[r * 72 + c + 2] = f2bf(f.z);
      T[r * 72 + c + 3] = f2bf(f.w);
    }
    __syncthreads();
    const int i = t >> 2, ck = t & 3;
    size_t orow = ((size_t)(e0 + i) << 10) + k0 + (ck << 4);
#pragma unroll
    for (int g = 0; g < 2; ++g) {
      unsigned short v[8];
#pragma unroll
      for (int j = 0; j < 8; ++j) v[j] = T[((ck << 4) + (g << 3) + j) * 72 + i];
      *(int4*)(Wt + orow + (g << 3)) = *(int4*)v;
    }
  }
}

// ---------------- 256x128 MFMA GEMM, 2-phase/K-tile counted pipeline -------
// 512 threads = 8 waves (2M x 4N); per-wave C = 128x32 (acc[8][2]).
// LDS: As 2x[256][64], Bs 2x[128][64] (swizzled) = 96KB -> 1 block/CU.
// Per K-tile t (buf = t&1):
//   phA: ds_read A-half0{rows 0-63,128-191}+all B; bar; 16 MFMA; bar
//   phB: ds_read A-half1; stage t+2{A0,B0,B1} (regions freed by phA);
//        bar; 16 MFMA; stage t+2{A1} (freed by phB reads); vmcnt(6); bar
// vmcnt(6) = t+2's six in-flight loads -> tile t+1 fully landed.
template <int MODE>
__global__ __launch_bounds__(512, 2) void gemm256_kernel(
    const unsigned short* __restrict__ A,
    const unsigned short* __restrict__ Bt,
    const float* __restrict__ b0, const float* __restrict__ b1,
    const float* __restrict__ b2,
    unsigned short* __restrict__ Oq, unsigned short* __restrict__ Ok,
    unsigned short* __restrict__ Ov, float* __restrict__ Of)
{
  __shared__ __align__(16) unsigned short As[32768];  // 2 x [256][64] swz
  __shared__ __align__(16) unsigned short Bs[16384];  // 2 x [128][64] swz

  const int tid = threadIdx.x;
  const int l   = tid & 63, w = tid >> 6;             // wave 0..7
  const int l15 = l & 15,  lg = l >> 4;
  const int wr  = w >> 2,  wc = w & 3;                // 2(M) x 4(N) waves
  const int m0  = blockIdx.y << 8, n0 = blockIdx.x << 7;
  const int srow = l >> 3;
  const int sblk = ((l & 7) ^ srow) << 3;
  const int rsw  = l15 & 7;
  const int bo0  = (lg ^ rsw) << 3;
  const int bo1  = ((4 + lg) ^ rsw) << 3;

  const unsigned short* gA = A  + (size_t)(m0 + srow) * 1024 + sblk;
  const unsigned short* gB = Bt + (size_t)(n0 + srow) * 1024 + sblk;

  // A-half h rows: {h*64..h*64+63} U {128+h*64..128+h*64+63}; 16 8-row segs,
  // wave w stages segs 2w,2w+1. B-half h rows: h*64 + w*8.
  auto STAGE_A = [&](int h, int kt, int pb) {
#pragma unroll
    for (int j = 0; j < 2; ++j) {
      int idx = (w << 1) + j;
      int rb = ((idx >> 3) << 7) + (h << 6) + ((idx & 7) << 3);
      gload_lds16(gA + (size_t)rb * 1024 + (kt << 6), &As[(pb << 14) + (rb << 6)]);
    }
  };
  auto STAGE_B = [&](int h, int kt, int pb) {
    int rb = (h << 6) + (w << 3);
    gload_lds16(gB + (size_t)rb * 1024 + (kt << 6), &Bs[(pb << 13) + (rb << 6)]);
  };

  floatx4 acc[8][2];
#pragma unroll
  for (int i = 0; i < 8; ++i)
#pragma unroll
    for (int j = 0; j < 2; ++j) acc[i][j] = (floatx4){0.f, 0.f, 0.f, 0.f};

  // ---- prologue: stage tiles 0 (buf0) and 1 (buf1); counted wait ----
  STAGE_A(0, 0, 0); STAGE_A(1, 0, 0); STAGE_B(0, 0, 0); STAGE_B(1, 0, 0);
  STAGE_A(0, 1, 1); STAGE_A(1, 1, 1); STAGE_B(0, 1, 1); STAGE_B(1, 1, 1);
  asm volatile("s_waitcnt vmcnt(6)" ::: "memory");    // tile 0 landed
  __builtin_amdgcn_s_barrier();

  const int NT = 16;                                  // K=1024 / 64
  for (int t = 0; t < NT; ++t) {
    const int pb = t & 1;
    const int Ab = pb << 14, Bb = pb << 13;
    const bool st = (t + 2 < NT);

    short8 af[4][2], bf[2][2];

    // ======== phase A: quadrant mh=0, both fn ========
#pragma unroll
    for (int fm = 0; fm < 4; ++fm) {
      const int ro = Ab + (((wr << 7) + (fm << 4) + l15) << 6);
      af[fm][0] = *(const short8*)&As[ro + bo0];
      af[fm][1] = *(const short8*)&As[ro + bo1];
    }
#pragma unroll
    for (int fn = 0; fn < 2; ++fn) {
      const int ro = Bb + (((wc << 5) + (fn << 4) + l15) << 6);
      bf[fn][0] = *(const short8*)&Bs[ro + bo0];
      bf[fn][1] = *(const short8*)&Bs[ro + bo1];
    }
    __builtin_amdgcn_s_barrier();
    __builtin_amdgcn_s_setprio(1);
#pragma unroll
    for (int fm = 0; fm < 4; ++fm)
#pragma unroll
      for (int fn = 0; fn < 2; ++fn) {
        acc[fm][fn] = __builtin_amdgcn_mfma_f32_16x16x32_bf16(af[fm][0], bf[fn][0], acc[fm][fn], 0, 0, 0);
        acc[fm][fn] = __builtin_amdgcn_mfma_f32_16x16x32_bf16(af[fm][1], bf[fn][1], acc[fm][fn], 0, 0, 0);
      }
    __builtin_amdgcn_s_setprio(0);
    __builtin_amdgcn_s_barrier();

    // ======== phase B: quadrant mh=1; stage tile t+2 ========
#pragma unroll
    for (int fm = 0; fm < 4; ++fm) {
      const int ro = Ab + (((wr << 7) + 64 + (fm << 4) + l15) << 6);
      af[fm][0] = *(const short8*)&As[ro + bo0];
      af[fm][1] = *(const short8*)&As[ro + bo1];
    }
    if (st) {                                         // regions freed by phA
      STAGE_A(0, t + 2, pb);
      STAGE_B(0, t + 2, pb);
      STAGE_B(1, t + 2, pb);
    }
    __builtin_amdgcn_s_barrier();
    __builtin_amdgcn_s_setprio(1);
#pragma unroll
    for (int fm = 0; fm < 4; ++fm)
#pragma unroll
      for (int fn = 0; fn < 2; ++fn) {
        acc[4 + fm][fn] = __builtin_amdgcn_mfma_f32_16x16x32_bf16(af[fm][0], bf[fn][0], acc[4 + fm][fn], 0, 0, 0);
        acc[4 + fm][fn] = __builtin_amdgcn_mfma_f32_16x16x32_bf16(af[fm][1], bf[fn][1], acc[4 + fm][fn], 0, 0, 0);
      }
    __builtin_amdgcn_s_setprio(0);
    if (st) STAGE_A(1, t + 2, pb);                    // region freed by phB reads
    if (st)              { asm volatile("s_waitcnt vmcnt(6)" ::: "memory"); }
    else if (t + 1 < NT) { asm volatile("s_waitcnt vmcnt(0)" ::: "memory"); }
    __builtin_amdgcn_s_barrier();
  }

  // ---- epilogue (verbatim scatter math from gemm128) ----
#pragma unroll
  for (int fn = 0; fn < 2; ++fn) {
    int c = n0 + (wc << 5) + (fn << 4) + l15;
    if (MODE == 1) {
      float bv = b0[c];
#pragma unroll
      for (int fm = 0; fm < 8; ++fm)
#pragma unroll
        for (int r = 0; r < 4; ++r) {
          int m = m0 + (wr << 7) + (fm << 4) + (lg << 2) + r;
          Of[((size_t)m << 10) + c] = acc[fm][fn][r] + bv;
        }
    } else {
      int proj = c >> 10, cc = c & 1023;              // wave-uniform
      int hn = cc >> 6, h = cc & 63;
      const float* bp = (proj == 0) ? b0 : (proj == 1) ? b1 : b2;
      float bv = bp[cc];
      float sc = (proj == 0) ? SCL : 1.0f;
      if (proj < 2) {
        unsigned short* O = (proj == 0) ? Oq : Ok;
#pragma unroll
        for (int fm = 0; fm < 8; ++fm)
#pragma unroll
          for (int r = 0; r < 4; ++r) {
            int m = m0 + (wr << 7) + (fm << 4) + (lg << 2) + r;
            int bb = m >> 11, ss = m & 2047;
            O[((((size_t)(bb << 4) + hn) << 11) + ss) * 64 + h] = f2bf((acc[fm][fn][r] + bv) * sc);
          }
      } else {                                        // V transposed: Vt[b][n][d][s]
#pragma unroll
        for (int fm = 0; fm < 8; ++fm) {
          int m = m0 + (wr << 7) + (fm << 4) + (lg << 2);
          int bb = m >> 11, ss = m & 2047;
          unsigned short p0 = f2bf(acc[fm][fn][0] + bv);
          unsigned short p1 = f2bf(acc[fm][fn][1] + bv);
          unsigned short p2 = f2bf(acc[fm][fn][2] + bv);
          unsigned short p3 = f2bf(acc[fm][fn][3] + bv);
          uint2 pk;
          pk.x = (unsigned int)p0 | ((unsigned int)p1 << 16);
          pk.y = (unsigned int)p2 | ((unsigned int)p3 << 16);
          *(uint2*)&Ov[((((size_t)(bb << 4) + hn) << 6) + h) * 2048 + ss] = pk;
        }
      }
    }
  }
}

// ---------------- MFMA flash attention v9b: flash9 + split fence -----------
// (round-16 verified: 77.6us) 1024 blocks x 256 threads; qt = 15-(x>>6) LPT;
// head = x&63 -> XCD = head%8. K dbuf 16KB; V single 8KB; Ps 16KB = 40KB.
// MID vmcnt(2) (V only; K flying through PV); END vmcnt(0).
__global__ __launch_bounds__(256, 4) void flash9_kernel(
    const unsigned short* __restrict__ Q,   // [B,N,S,D], pre-scaled by SCL
    const unsigned short* __restrict__ K,   // [B,N,S,D]
    const unsigned short* __restrict__ Vt,  // [B,N,D,S]
    unsigned short* __restrict__ Z)         // [B,S,N*D]
{
  __shared__ __align__(16) unsigned short Ks[8192];   // 2 x [64 key][64 d] swz
  __shared__ __align__(16) unsigned short Vs[4096];   // [64 d][64 key] swz
  __shared__ __align__(16) unsigned short Ps[8192];   // 4 waves x [32 q][64 k] swz

  const int tid = threadIdx.x;
  const int l   = tid & 63, w = tid >> 6;             // w in {0,1,2,3}
  const int l15 = l & 15,  lg = l >> 4;
  const int x    = blockIdx.x;
  const int qt   = 15 - (x >> 6);                     // 128-row q-tile, longest first
  const int head = x & 63;
  const int n = head & 15, b = head >> 4;
  const size_t hoff = (size_t)head << 17;
  const unsigned short* Qh = Q + hoff;
  const unsigned short* Kh = K + hoff;
  const unsigned short* Vh = Vt + hoff;
  unsigned short* Psw = Ps + (w << 11);

  const int srow8 = l >> 3;
  const int sblk8 = ((l & 7) ^ srow8) << 3;
  const int swz   = l15 & 7;
  const int bo0   = (lg ^ swz) << 3;
  const int bo1   = ((4 + lg) ^ swz) << 3;

  const unsigned short* gK = Kh + (size_t)(((w << 4) + srow8) << 6) + sblk8;
  const unsigned short* gV = Vh + (size_t)(((w << 4) + srow8) << 11) + sblk8;
  unsigned short* ldsK0 = &Ks[w << 10];
  unsigned short* ldsV0 = &Vs[w << 10];

  uint2* pw[2][4];
  const short8* pr[2][2];
#pragma unroll
  for (int qc = 0; qc < 2; ++qc) {
    const int rbase = ((qc << 4) + l15) << 6;
#pragma unroll
    for (int mc = 0; mc < 4; ++mc)
      pw[qc][mc] = (uint2*)&Psw[rbase + (((((mc << 1) + (lg >> 1)) ^ swz) << 3) + ((lg & 1) << 2))];
#pragma unroll
    for (int kc = 0; kc < 2; ++kc)
      pr[qc][kc] = (const short8*)&Psw[rbase + ((((kc << 2) + lg) ^ swz) << 3)];
  }

  short8 onef;
#pragma unroll
  for (int i = 0; i < 8; ++i) onef[i] = (short)0x3F80;   // bf16 1.0

  floatx4 z4 = (floatx4){0.f, 0.f, 0.f, 0.f};
  asm volatile("" : "+v"(z4));

  const int q0w = (qt << 7) + (w << 5);

  short8 qf[2][2];
#pragma unroll
  for (int qc = 0; qc < 2; ++qc)
#pragma unroll
    for (int dh = 0; dh < 2; ++dh)
      qf[qc][dh] = *(const short8*)(Qh + (size_t)(q0w + (qc << 4) + l15) * 64 + (dh << 5) + (lg << 3));

  floatx4 acc_o[2][4], acc_l[2];
#pragma unroll
  for (int qc = 0; qc < 2; ++qc) {
    acc_l[qc] = (floatx4){0.f, 0.f, 0.f, 0.f};
#pragma unroll
    for (int dc = 0; dc < 4; ++dc) acc_o[qc][dc] = (floatx4){0.f, 0.f, 0.f, 0.f};
  }

  gload_lds16(gK,       ldsK0);
  gload_lds16(gK + 512, ldsK0 + 512);
  asm volatile("s_waitcnt vmcnt(0)" ::: "memory");
  __builtin_amdgcn_s_barrier();

  int buf = 0;
  const int nkt = (qt << 1) + 2;
  for (int kt = 0; kt < nkt; ++kt) {
    const int k0 = kt << 6;

    {
      const unsigned short* pV = gV + k0;
      gload_lds16(pV,          ldsV0);
      gload_lds16(pV + 16384,  ldsV0 + 512);
    }
    if (kt + 1 < nkt) {
      const unsigned short* pK = gK + ((size_t)(kt + 1) << 12);
      unsigned short* d = ldsK0 + ((buf ^ 1) << 12);
      gload_lds16(pK,       d);
      gload_lds16(pK + 512, d + 512);
    }

    const bool active = (k0 <= q0w + 31);
    if (active) {
      const int cb = buf << 12;

      floatx4 s0[4], s1[4];
      __builtin_amdgcn_s_setprio(1);
#pragma unroll
      for (int mc = 0; mc < 4; ++mc) {
        short8 ak = *(const short8*)&Ks[cb + (((mc << 4) + l15) << 6) + bo0];
        s0[mc] = __builtin_amdgcn_mfma_f32_16x16x32_bf16(ak, qf[0][0], z4, 0, 0, 0);
        s1[mc] = __builtin_amdgcn_mfma_f32_16x16x32_bf16(ak, qf[1][0], z4, 0, 0, 0);
      }
#pragma unroll
      for (int mc = 0; mc < 4; ++mc) {
        short8 ak = *(const short8*)&Ks[cb + (((mc << 4) + l15) << 6) + bo1];
        s0[mc] = __builtin_amdgcn_mfma_f32_16x16x32_bf16(ak, qf[0][1], s0[mc], 0, 0, 0);
        s1[mc] = __builtin_amdgcn_mfma_f32_16x16x32_bf16(ak, qf[1][1], s1[mc], 0, 0, 0);
      }
      __builtin_amdgcn_s_setprio(0);

      const bool needmask = (k0 + 63 > q0w);
#pragma unroll
      for (int qc = 0; qc < 2; ++qc) {
        const int qg = q0w + (qc << 4) + l15;
#pragma unroll
        for (int mc = 0; mc < 4; ++mc) {
          float p[4];
#pragma unroll
          for (int r = 0; r < 4; ++r) {
            float e = exp2f(qc ? s1[mc][r] : s0[mc][r]);
            if (needmask) {
              int key = k0 + (mc << 4) + (lg << 2) + r;
              e = (key > qg) ? 0.f : e;
            }
            p[r] = e;
          }
          uint2 pk;
          asm("v_cvt_pk_bf16_f32 %0, %1, %2" : "=v"(pk.x) : "v"(p[0]), "v"(p[1]));
          asm("v_cvt_pk_bf16_f32 %0, %1, %2" : "=v"(pk.y) : "v"(p[2]), "v"(p[3]));
          *pw[qc][mc] = pk;
        }
      }
    }

    if (kt + 1 < nkt) { asm volatile("s_waitcnt vmcnt(2)" ::: "memory"); }
    else              { asm volatile("s_waitcnt vmcnt(0)" ::: "memory"); }
    __builtin_amdgcn_s_barrier();

    if (active) {
      short8 pa[2][2];
#pragma unroll
      for (int qc = 0; qc < 2; ++qc)
#pragma unroll
        for (int kc = 0; kc < 2; ++kc)
          pa[qc][kc] = *pr[qc][kc];
      __builtin_amdgcn_s_setprio(1);
#pragma unroll
      for (int kc = 0; kc < 2; ++kc) {
        const int bo = kc ? bo1 : bo0;
#pragma unroll
        for (int dc = 0; dc < 4; ++dc) {
          short8 vb = *(const short8*)&Vs[(((dc << 4) + l15) << 6) + bo];
          acc_o[0][dc] = __builtin_amdgcn_mfma_f32_16x16x32_bf16(pa[0][kc], vb, acc_o[0][dc], 0, 0, 0);
          acc_o[1][dc] = __builtin_amdgcn_mfma_f32_16x16x32_bf16(pa[1][kc], vb, acc_o[1][dc], 0, 0, 0);
        }
        acc_l[0] = __builtin_amdgcn_mfma_f32_16x16x32_bf16(pa[0][kc], onef, acc_l[0], 0, 0, 0);
        acc_l[1] = __builtin_amdgcn_mfma_f32_16x16x32_bf16(pa[1][kc], onef, acc_l[1], 0, 0, 0);
      }
      __builtin_amdgcn_s_setprio(0);
    }

    asm volatile("s_waitcnt vmcnt(0)" ::: "memory");
    __builtin_amdgcn_s_barrier();
    buf ^= 1;
  }

#pragma unroll
  for (int qc = 0; qc < 2; ++qc) {
    floatx4 inv;
#pragma unroll
    for (int r = 0; r < 4; ++r) inv[r] = 1.f / acc_l[qc][r];
#pragma unroll
    for (int dc = 0; dc < 4; ++dc)
#pragma unroll
      for (int r = 0; r < 4; ++r) {
        int qg = q0w + (qc << 4) + (lg << 2) + r;
        Z[(((size_t)b << 11) + qg) * 1024 + (n << 6) + (dc << 4) + l15] =
            f2bf(acc_o[qc][dc][r] * inv[r]);
      }
  }
}

// ---------------------------------------------------------------------------
extern "C" void kernel_launch(void* const* d_in, const int* in_sizes, int n_in,
                              void* d_out, int out_size, void* d_ws, size_t ws_size,
                              hipStream_t stream) {
  const float* x   = (const float*)d_in[0];
  const float* W_Q = (const float*)d_in[1];
  const float* b_Q = (const float*)d_in[2];
  const float* W_K = (const float*)d_in[3];
  const float* b_K = (const float*)d_in[4];
  const float* W_V = (const float*)d_in[5];
  const float* b_V = (const float*)d_in[6];
  const float* W_O = (const float*)d_in[7];
  const float* b_O = (const float*)d_in[8];
  float* out = (float*)d_out;

  unsigned short* ws    = (unsigned short*)d_ws;
  unsigned short* BtQKV = ws;                        // [3072][1024]
  unsigned short* Wo_t  = BtQKV + (3u << 20);        // [1024][1024]
  unsigned short* Xb    = Wo_t + (1u << 20);         // [8192][1024]
  unsigned short* Qb    = Xb + (8u << 20);           // [B,N,S,D]
  unsigned short* Kb    = Qb + (8u << 20);
  unsigned short* Vtb   = Kb + (8u << 20);           // [B,N,D,S]
  unsigned short* Zb    = Vtb + (8u << 20);          // [B,S,N*D]

  prep_kernel<<<9216, 256, 0, stream>>>(x, Xb, W_Q, W_K, W_V, BtQKV, W_O, Wo_t);

  gemm256_kernel<0><<<dim3(24, 32), 512, 0, stream>>>(
      Xb, BtQKV, b_Q, b_K, b_V, Qb, Kb, Vtb, nullptr);

  flash9_kernel<<<1024, 256, 0, stream>>>(Qb, Kb, Vtb, Zb);

  gemm256_kernel<1><<<dim3(8, 32), 512, 0, stream>>>(
      Zb, Wo_t, b_O, nullptr, nullptr, nullptr, nullptr, nullptr, out);
}